// Round 9
// baseline (222.770 us; speedup 1.0000x reference)
//
#include <hip/hip_runtime.h>
#include <hip/hip_bf16.h>

typedef __attribute__((ext_vector_type(8))) short bf16x8;
typedef __attribute__((ext_vector_type(4))) float f32x4;
typedef __attribute__((ext_vector_type(16))) float f32x16;

#define Bsz 8192
#define Ksz 1024
#define Dsz 64
#define Nsz 4096  // d*d

__device__ __forceinline__ void async_load16(const void* g, void* lds) {
    __builtin_amdgcn_global_load_lds(
        (const __attribute__((address_space(1))) void*)g,
        (__attribute__((address_space(3))) void*)lds,
        16, 0, 0);
}

__device__ __forceinline__ float bf2f(unsigned short s) {
    union { unsigned u; float f; } x;
    x.u = ((unsigned)s) << 16;
    return x.f;
}

// ---------------------------------------------------------------------------
// Kernel 1: G [K=1024][N=4096] f32  ->  Gt [N=4096][K=1024] bf16 (transposed)
// ---------------------------------------------------------------------------
__global__ __launch_bounds__(256) void transpose_convert(
    const float* __restrict__ G, __hip_bfloat16* __restrict__ Gt)
{
    __shared__ float tile[64][65];
    const int t = threadIdx.x;
    const int n0 = blockIdx.x * 64;  // N tile
    const int k0 = blockIdx.y * 64;  // K tile

    for (int i = 0; i < 4; ++i) {
        int f4 = t + 256 * i;
        int row = f4 >> 4;
        int c4  = (f4 & 15) << 2;
        float4 v = *(const float4*)&G[(size_t)(k0 + row) * Nsz + n0 + c4];
        tile[row][c4 + 0] = v.x;
        tile[row][c4 + 1] = v.y;
        tile[row][c4 + 2] = v.z;
        tile[row][c4 + 3] = v.w;
    }
    __syncthreads();
    for (int i = 0; i < 4; ++i) {
        int o = t + 256 * i;
        int rowp = o >> 4;
        int c4   = (o & 15) << 2;
        union { ushort4 u; __hip_bfloat16 h[4]; } cvt;
        cvt.h[0] = __float2bfloat16(tile[c4 + 0][rowp]);
        cvt.h[1] = __float2bfloat16(tile[c4 + 1][rowp]);
        cvt.h[2] = __float2bfloat16(tile[c4 + 2][rowp]);
        cvt.h[3] = __float2bfloat16(tile[c4 + 3][rowp]);
        *(ushort4*)&Gt[(size_t)(n0 + rowp) * Ksz + k0 + c4] = cvt.u;
    }
}

// ---------------------------------------------------------------------------
// Kernel 2: weights via MFMA with split-bf16 (hi+lo) precision. (unchanged)
// ---------------------------------------------------------------------------
#define QSTR 72

__global__ __launch_bounds__(256) void weights_mfma(
    const float* __restrict__ q, const float* __restrict__ c,
    const float* __restrict__ bw, __hip_bfloat16* __restrict__ W)
{
    __shared__ __attribute__((aligned(16))) __hip_bfloat16 qh[128 * QSTR];
    __shared__ __attribute__((aligned(16))) __hip_bfloat16 ql[128 * QSTR];
    __shared__ __attribute__((aligned(16))) __hip_bfloat16 ch[128 * QSTR];
    __shared__ __attribute__((aligned(16))) __hip_bfloat16 cl[128 * QSTR];
    __shared__ float sqq[128];
    __shared__ float sqc[128];

    const int t  = threadIdx.x;
    const int b0 = blockIdx.x * 128;
    const int k0 = blockIdx.y * 128;

    for (int i = 0; i < 8; ++i) {
        int f4  = t + 256 * i;
        int row = f4 >> 4;
        int c4  = (f4 & 15) << 2;
        float4 v = *(const float4*)&q[(size_t)(b0 + row) * Dsz + c4];
        float4 u = *(const float4*)&c[(size_t)(k0 + row) * Dsz + c4];
        float qv[4] = {v.x, v.y, v.z, v.w};
        float cv[4] = {2.f * u.x, 2.f * u.y, 2.f * u.z, 2.f * u.w};
        union { ushort4 u4; __hip_bfloat16 h[4]; } qhh, qll, chh, cll;
        #pragma unroll
        for (int e = 0; e < 4; ++e) {
            __hip_bfloat16 hb = __float2bfloat16(qv[e]);
            qhh.h[e] = hb;
            qll.h[e] = __float2bfloat16(qv[e] - bf2f(*(unsigned short*)&hb));
            __hip_bfloat16 hc = __float2bfloat16(cv[e]);
            chh.h[e] = hc;
            cll.h[e] = __float2bfloat16(cv[e] - bf2f(*(unsigned short*)&hc));
        }
        *(ushort4*)&qh[row * QSTR + c4] = qhh.u4;
        *(ushort4*)&ql[row * QSTR + c4] = qll.u4;
        *(ushort4*)&ch[row * QSTR + c4] = chh.u4;
        *(ushort4*)&cl[row * QSTR + c4] = cll.u4;
    }
    __syncthreads();

    if (t < 128) {
        float s = 0.f;
        for (int x8 = 0; x8 < 64; x8 += 8) {
            bf16x8 h = *(const bf16x8*)&qh[t * QSTR + x8];
            bf16x8 l = *(const bf16x8*)&ql[t * QSTR + x8];
            #pragma unroll
            for (int e = 0; e < 8; ++e) {
                float v = bf2f((unsigned short)h[e]) + bf2f((unsigned short)l[e]);
                s += v * v;
            }
        }
        sqq[t] = s;
    } else {
        int r = t - 128;
        float s = 0.f;
        for (int x8 = 0; x8 < 64; x8 += 8) {
            bf16x8 h = *(const bf16x8*)&ch[r * QSTR + x8];
            bf16x8 l = *(const bf16x8*)&cl[r * QSTR + x8];
            #pragma unroll
            for (int e = 0; e < 8; ++e) {
                float v = 0.5f * (bf2f((unsigned short)h[e]) + bf2f((unsigned short)l[e]));
                s += v * v;
            }
        }
        sqc[r] = s;
    }
    __syncthreads();

    const int wave = t >> 6;
    const int lane = t & 63;
    const int wm = (wave >> 1) * 64;
    const int wn = (wave & 1) * 64;
    const int lrow = lane & 15;
    const int lk8  = (lane >> 4) << 3;

    f32x4 acc[4][4];
    for (int i = 0; i < 4; ++i)
        for (int j = 0; j < 4; ++j) acc[i][j] = (f32x4){0.f, 0.f, 0.f, 0.f};

    #pragma unroll
    for (int ks = 0; ks < 64; ks += 32) {
        bf16x8 ah[4], al[4], bh[4], bl[4];
        #pragma unroll
        for (int i = 0; i < 4; ++i) {
            int ra = (wm + i * 16 + lrow) * QSTR + ks + lk8;
            int rb = (wn + i * 16 + lrow) * QSTR + ks + lk8;
            ah[i] = *(const bf16x8*)&qh[ra];
            al[i] = *(const bf16x8*)&ql[ra];
            bh[i] = *(const bf16x8*)&ch[rb];
            bl[i] = *(const bf16x8*)&cl[rb];
        }
        #pragma unroll
        for (int i = 0; i < 4; ++i)
            #pragma unroll
            for (int j = 0; j < 4; ++j) {
                acc[i][j] = __builtin_amdgcn_mfma_f32_16x16x32_bf16(ah[i], bh[j], acc[i][j], 0, 0, 0);
                acc[i][j] = __builtin_amdgcn_mfma_f32_16x16x32_bf16(ah[i], bl[j], acc[i][j], 0, 0, 0);
                acc[i][j] = __builtin_amdgcn_mfma_f32_16x16x32_bf16(al[i], bh[j], acc[i][j], 0, 0, 0);
            }
    }

    const int crow = (lane >> 4) << 2;
    const int ccol = lane & 15;
    for (int j = 0; j < 4; ++j) {
        int k = wn + j * 16 + ccol;
        float bwv = bw[k0 + k];
        float sc  = sqc[k];
        #pragma unroll
        for (int i = 0; i < 4; ++i) {
            #pragma unroll
            for (int r = 0; r < 4; ++r) {
                int b = wm + i * 16 + crow + r;
                float d2 = fmaxf(sqq[b] + sc - acc[i][j][r], 0.f);
                W[(size_t)(b0 + b) * Ksz + (k0 + k)] = __float2bfloat16(__expf(-bwv * d2));
            }
        }
    }
}

// ---------------------------------------------------------------------------
// Kernel 3: C[M][N] = A[M][K] * Bt[N][K]^T  (bf16 in, f32 out)
// r7 champion schedule (83.6 us), single change: MFMA shape 16x16x32 ->
// 32x32x16 (ubench ceiling 2075->2495 TF, half the MFMA instructions).
// Same LDS layout/staging/swizzle/vmcnt/lgkm counts; fragment mapping:
//   A: row = lane&31, k-chunk = lane>>5 (8 contiguous bf16)
//   B: col = lane&31, k-chunk = lane>>5
//   C/D: col = lane&31, row = (reg&3) + 8*(reg>>2) + 4*(lane>>5)  [m74/m101]
// Per quad (A-half x B-half): 2 m-frags x 4 ksteps = 8 MFMA (was 16).
// Read counts per phase UNCHANGED (A-half: 8 b128, B-half: 4 b128).
// Epilogue: plain stores (champion behavior), 32-col contiguous spans.
// ---------------------------------------------------------------------------
#define TM2 256
#define TN2 256
#define BK2 64
#define NT2 16            // K-tiles

#define BAR()  __builtin_amdgcn_s_barrier()

#define MFMA_QUAD(Aa, Bb, MO, BH)                                              \
    _Pragma("unroll")                                                          \
    for (int ks2 = 0; ks2 < 4; ++ks2)                                          \
        _Pragma("unroll")                                                      \
        for (int m = 0; m < 2; ++m)                                            \
            acc[MO + m][BH] = __builtin_amdgcn_mfma_f32_32x32x16_bf16(         \
                Aa[ks2][m], Bb[ks2], acc[MO + m][BH], 0, 0, 0);

__global__ __launch_bounds__(512, 2) void gemm_8ph(
    const __hip_bfloat16* __restrict__ A,   // W  [M][K]
    const __hip_bfloat16* __restrict__ Bt,  // Gt [N][K]
    float* __restrict__ C)                  // [M][N]
{
    __shared__ __attribute__((aligned(16))) __hip_bfloat16 As[2 * 2 * 128 * 64]; // 64 KB
    __shared__ __attribute__((aligned(16))) __hip_bfloat16 Bs[2 * 2 * 128 * 64]; // 64 KB

    const int t    = threadIdx.x;
    const int wave = t >> 6;
    const int lane = t & 63;

    // T1: bijective XCD swizzle (512 wgs, 8 XCDs, 64 per XCD; bx fastest for
    // A-panel reuse within the XCD chunk)
    const int wg  = blockIdx.x;
    const int swz = (wg & 7) * 64 + (wg >> 3);
    const int bx  = swz & 15;          // N: 4096/256 = 16
    const int by  = swz >> 4;          // M: 8192/256 = 32
    const int m0  = by * TM2;
    const int n0  = bx * TN2;

    const int wm   = (wave >> 2) * 128;  // 0 or 128
    const int wn   = (wave & 3) * 64;    // 0,64,128,192
    const int l31  = lane & 31;
    const int kh   = lane >> 5;          // 0..1 (k-half of the 16-k step)

    f32x16 acc[4][2];
    #pragma unroll
    for (int i = 0; i < 4; ++i)
        #pragma unroll
        for (int j = 0; j < 2; ++j)
            #pragma unroll
            for (int e = 0; e < 16; ++e) acc[i][j][e] = 0.f;

    // --- staging: one half = 128 lds-rows x 64 bf16 = 1024 chunks of 16 B;
    //     2 global_load_lds per thread. LDS dest linear; XOR swizzle applied
    //     on the GLOBAL source column-chunk (both-sides rule). K-index wraps
    //     mod 16 so dummy tail stages stay in-bounds.
    auto stageA = [&](int tt, int h) {
        __hip_bfloat16* lds = &As[(((tt & 1) << 1) + h) * 8192];
        const int row0 = m0 + (h << 6);
        const int kcol = (tt & 15) << 6;
        #pragma unroll
        for (int l = 0; l < 2; ++l) {
            int ch   = (l << 9) + t;
            int rl   = ch >> 3;
            int g8   = (ch & 7) ^ (rl & 7);
            int grow = row0 + ((rl >> 6) << 7) + (rl & 63);
            async_load16(A + (size_t)grow * Ksz + kcol + (g8 << 3), lds + (ch << 3));
        }
    };
    auto stageB = [&](int tt, int h) {
        __hip_bfloat16* lds = &Bs[(((tt & 1) << 1) + h) * 8192];
        const int row0 = n0 + (h << 5);
        const int kcol = (tt & 15) << 6;
        #pragma unroll
        for (int l = 0; l < 2; ++l) {
            int ch   = (l << 9) + t;
            int rl   = ch >> 3;
            int g8   = (ch & 7) ^ (rl & 7);
            int grow = row0 + ((rl >> 5) << 6) + (rl & 31);
            async_load16(Bt + (size_t)grow * Ksz + kcol + (g8 << 3), lds + (ch << 3));
        }
    };

    // Fragment sets: aX[kstep][mfrag], bX[kstep]
    bf16x8 aC[4][2], aN[4][2], b0[4], b1[4];

    auto readA = [&](bf16x8 (&a)[4][2], int bb, int mh) {
        const __hip_bfloat16* base = &As[((bb << 1) + mh) * 8192];
        #pragma unroll
        for (int ks2 = 0; ks2 < 4; ++ks2)
            #pragma unroll
            for (int m = 0; m < 2; ++m) {
                int rl = (wm >> 1) + m * 32 + l31;
                int cc = ((((ks2 << 1) + kh) ^ (rl & 7)) << 3);
                a[ks2][m] = *(const bf16x8*)&base[rl * 64 + cc];
            }
    };
    auto readB = [&](bf16x8 (&b)[4], int bb, int nh) {
        const __hip_bfloat16* base = &Bs[((bb << 1) + nh) * 8192];
        #pragma unroll
        for (int ks2 = 0; ks2 < 4; ++ks2) {
            int rl = (wn >> 1) + l31;
            int cc = ((((ks2 << 1) + kh) ^ (rl & 7)) << 3);
            b[ks2] = *(const bf16x8*)&base[rl * 64 + cc];
        }
    };

    // --- prologue. Stage order defines the vmcnt queue:
    //     [A0(0), B0(0) | B1(0), A1(0), A0(1), B0(1), B1(1)]  (14 loads)
    //     vmcnt(10) forces A0(0),B0(0) -> pre-loop fragment reads are safe.
    stageA(0, 0); stageB(0, 0);
    stageB(0, 1); stageA(0, 1); stageA(1, 0); stageB(1, 0); stageB(1, 1);
    asm volatile("s_waitcnt vmcnt(10)" ::: "memory");
    BAR();
    readA(aC, 0, 0);
    readB(b0, 0, 0);          // 12 ds_reads in flight into regs

    #pragma unroll 2
    for (int tt = 0; tt < NT2; ++tt) {
        const int buf = tt & 1;

        // ---- phase 0: Q0(aC,b0) [read last ph3]; prefetch b1 <- B1(t)
        asm volatile("s_waitcnt vmcnt(8)" ::: "memory");   // B1(t) landed
        BAR();
        readB(b1, buf, 1);                                  // 4 ds
        stageA(tt + 1, 1);
        asm volatile("s_waitcnt lgkmcnt(4)" ::: "memory");  // aC/b0 done, b1 flies
        __builtin_amdgcn_s_setprio(1);
        MFMA_QUAD(aC, b0, 0, 0);
        __builtin_amdgcn_s_setprio(0);
        BAR();

        // ---- phase 1: Q1(aC,b1); prefetch aN <- A1(t)
        asm volatile("s_waitcnt vmcnt(8)" ::: "memory");   // A1(t) landed
        BAR();
        readA(aN, buf, 1);                                  // 8 ds
        stageA(tt + 2, 0);
        asm volatile("s_waitcnt lgkmcnt(8)" ::: "memory");  // b1 done, aN flies
        __builtin_amdgcn_s_setprio(1);
        MFMA_QUAD(aC, b1, 0, 1);
        __builtin_amdgcn_s_setprio(0);
        BAR();

        // ---- phase 2: Q2(aN,b1); no reads
        stageB(tt + 2, 0);
        BAR();
        asm volatile("s_waitcnt lgkmcnt(0)" ::: "memory");  // aN done (had ph1 to land)
        __builtin_amdgcn_s_setprio(1);
        MFMA_QUAD(aN, b1, 2, 1);
        __builtin_amdgcn_s_setprio(0);
        BAR();

        // ---- phase 3: Q3(aN,b0); cross-tile prefetch aC/b0 <- t+1
        stageB(tt + 2, 1);
        asm volatile("s_waitcnt vmcnt(10)" ::: "memory");  // A0(t+1),B0(t+1) landed
        BAR();
        __builtin_amdgcn_s_setprio(1);
        MFMA_QUAD(aN, b0, 2, 0);    // register-only; WAR keeps it before reads
        __builtin_amdgcn_s_setprio(0);
        readA(aC, buf ^ 1, 0);                              // 8 ds (next tile)
        readB(b0, buf ^ 1, 0);                              // 4 ds (next tile)
        BAR();
    }

    // --- epilogue: 32x32 C/D layout: col = lane&31,
    //     row = (reg&3) + 8*(reg>>2) + 4*(lane>>5). Plain stores.
    #pragma unroll
    for (int bh = 0; bh < 2; ++bh) {
        int gn = n0 + wn + bh * 32 + l31;
        float diag = (gn % 65 == 0) ? 0.001f : 0.f;
        #pragma unroll
        for (int idx = 0; idx < 4; ++idx) {
            int gmb = m0 + wm + ((idx >> 1) << 6) + ((idx & 1) << 5) + (kh << 2);
            #pragma unroll
            for (int reg = 0; reg < 16; ++reg) {
                int gm = gmb + (reg & 3) + ((reg >> 2) << 3);
                C[(size_t)gm * Nsz + gn] = acc[idx][bh][reg] + diag;
            }
        }
    }
}

// ---------------------------------------------------------------------------
extern "C" void kernel_launch(void* const* d_in, const int* in_sizes, int n_in,
                              void* d_out, int out_size, void* d_ws, size_t ws_size,
                              hipStream_t stream) {
    const float* q  = (const float*)d_in[0];
    const float* c  = (const float*)d_in[1];
    const float* bw = (const float*)d_in[2];
    const float* G  = (const float*)d_in[3];
    float* out = (float*)d_out;

    __hip_bfloat16* W  = (__hip_bfloat16*)d_ws;                        // 16 MB
    __hip_bfloat16* Gt = (__hip_bfloat16*)((char*)d_ws + (size_t)16 * 1024 * 1024); // 8 MB

    transpose_convert<<<dim3(Nsz / 64, Ksz / 64), 256, 0, stream>>>(G, Gt);
    weights_mfma<<<dim3(Bsz / 128, Ksz / 128), 256, 0, stream>>>(q, c, bw, W);
    gemm_8ph<<<dim3((Bsz / TM2) * (Nsz / TN2)), 512, 0, stream>>>(W, Gt, out);
}

// Round 10
// 217.447 us; speedup vs baseline: 1.0245x; 1.0245x over previous
//
#include <hip/hip_runtime.h>
#include <hip/hip_bf16.h>

typedef __attribute__((ext_vector_type(8))) short bf16x8;
typedef __attribute__((ext_vector_type(4))) float f32x4;

#define Bsz 8192
#define Ksz 1024
#define Dsz 64
#define Nsz 4096  // d*d

__device__ __forceinline__ void async_load16(const void* g, void* lds) {
    __builtin_amdgcn_global_load_lds(
        (const __attribute__((address_space(1))) void*)g,
        (__attribute__((address_space(3))) void*)lds,
        16, 0, 0);
}

__device__ __forceinline__ float bf2f(unsigned short s) {
    union { unsigned u; float f; } x;
    x.u = ((unsigned)s) << 16;
    return x.f;
}

// ---------------------------------------------------------------------------
// FUSED prep kernel: blocks [0,512) run the weights_mfma body; blocks
// [512,1536) run the transpose_convert body. Bodies are byte-identical to the
// proven standalone kernels (LDS carved from a shared union). The two roles
// touch disjoint inputs/outputs -> overlap across CUs + one fewer dispatch.
// LDS union: weights needs 74752 B (4x 128*72 bf16 + 2x 128 f32);
//            transpose needs 16640 B (64x65 f32). Block-uniform branch.
// ---------------------------------------------------------------------------
#define QSTR 72

__global__ __launch_bounds__(256) void prep_fused(
    const float* __restrict__ q, const float* __restrict__ c,
    const float* __restrict__ bw, const float* __restrict__ G,
    __hip_bfloat16* __restrict__ W, __hip_bfloat16* __restrict__ Gt)
{
    __shared__ __attribute__((aligned(16))) char smem[74752];
    const int t = threadIdx.x;

    if (blockIdx.x >= 512) {
        // ---------------- transpose role ----------------
        const int tb = blockIdx.x - 512;
        const int n0 = (tb & 63) * 64;   // N tile
        const int k0 = (tb >> 6) * 64;   // K tile
        float (*tile)[65] = (float(*)[65])smem;

        for (int i = 0; i < 4; ++i) {
            int f4 = t + 256 * i;
            int row = f4 >> 4;
            int c4  = (f4 & 15) << 2;
            float4 v = *(const float4*)&G[(size_t)(k0 + row) * Nsz + n0 + c4];
            tile[row][c4 + 0] = v.x;
            tile[row][c4 + 1] = v.y;
            tile[row][c4 + 2] = v.z;
            tile[row][c4 + 3] = v.w;
        }
        __syncthreads();
        for (int i = 0; i < 4; ++i) {
            int o = t + 256 * i;
            int rowp = o >> 4;
            int c4   = (o & 15) << 2;
            union { ushort4 u; __hip_bfloat16 h[4]; } cvt;
            cvt.h[0] = __float2bfloat16(tile[c4 + 0][rowp]);
            cvt.h[1] = __float2bfloat16(tile[c4 + 1][rowp]);
            cvt.h[2] = __float2bfloat16(tile[c4 + 2][rowp]);
            cvt.h[3] = __float2bfloat16(tile[c4 + 3][rowp]);
            *(ushort4*)&Gt[(size_t)(n0 + rowp) * Ksz + k0 + c4] = cvt.u;
        }
        return;
    }

    // ---------------- weights role ----------------
    const int wb = blockIdx.x;
    const int b0 = (wb & 63) * 128;
    const int k0 = (wb >> 6) * 128;

    __hip_bfloat16* qh = (__hip_bfloat16*)smem;           // 128*QSTR
    __hip_bfloat16* ql = qh + 128 * QSTR;
    __hip_bfloat16* ch = ql + 128 * QSTR;
    __hip_bfloat16* cl = ch + 128 * QSTR;
    float* sqq = (float*)(cl + 128 * QSTR);               // 128 f32
    float* sqc = sqq + 128;                               // 128 f32

    for (int i = 0; i < 8; ++i) {
        int f4  = t + 256 * i;
        int row = f4 >> 4;
        int c4  = (f4 & 15) << 2;
        float4 v = *(const float4*)&q[(size_t)(b0 + row) * Dsz + c4];
        float4 u = *(const float4*)&c[(size_t)(k0 + row) * Dsz + c4];
        float qv[4] = {v.x, v.y, v.z, v.w};
        float cv[4] = {2.f * u.x, 2.f * u.y, 2.f * u.z, 2.f * u.w};
        union { ushort4 u4; __hip_bfloat16 h[4]; } qhh, qll, chh, cll;
        #pragma unroll
        for (int e = 0; e < 4; ++e) {
            __hip_bfloat16 hb = __float2bfloat16(qv[e]);
            qhh.h[e] = hb;
            qll.h[e] = __float2bfloat16(qv[e] - bf2f(*(unsigned short*)&hb));
            __hip_bfloat16 hc = __float2bfloat16(cv[e]);
            chh.h[e] = hc;
            cll.h[e] = __float2bfloat16(cv[e] - bf2f(*(unsigned short*)&hc));
        }
        *(ushort4*)&qh[row * QSTR + c4] = qhh.u4;
        *(ushort4*)&ql[row * QSTR + c4] = qll.u4;
        *(ushort4*)&ch[row * QSTR + c4] = chh.u4;
        *(ushort4*)&cl[row * QSTR + c4] = cll.u4;
    }
    __syncthreads();

    if (t < 128) {
        float s = 0.f;
        for (int x8 = 0; x8 < 64; x8 += 8) {
            bf16x8 h = *(const bf16x8*)&qh[t * QSTR + x8];
            bf16x8 l = *(const bf16x8*)&ql[t * QSTR + x8];
            #pragma unroll
            for (int e = 0; e < 8; ++e) {
                float v = bf2f((unsigned short)h[e]) + bf2f((unsigned short)l[e]);
                s += v * v;
            }
        }
        sqq[t] = s;
    } else {
        int r = t - 128;
        float s = 0.f;
        for (int x8 = 0; x8 < 64; x8 += 8) {
            bf16x8 h = *(const bf16x8*)&ch[r * QSTR + x8];
            bf16x8 l = *(const bf16x8*)&cl[r * QSTR + x8];
            #pragma unroll
            for (int e = 0; e < 8; ++e) {
                float v = 0.5f * (bf2f((unsigned short)h[e]) + bf2f((unsigned short)l[e]));
                s += v * v;
            }
        }
        sqc[r] = s;
    }
    __syncthreads();

    const int wave = t >> 6;
    const int lane = t & 63;
    const int wm = (wave >> 1) * 64;
    const int wn = (wave & 1) * 64;
    const int lrow = lane & 15;
    const int lk8  = (lane >> 4) << 3;

    f32x4 acc[4][4];
    for (int i = 0; i < 4; ++i)
        for (int j = 0; j < 4; ++j) acc[i][j] = (f32x4){0.f, 0.f, 0.f, 0.f};

    #pragma unroll
    for (int ks = 0; ks < 64; ks += 32) {
        bf16x8 ah[4], al[4], bh[4], bl[4];
        #pragma unroll
        for (int i = 0; i < 4; ++i) {
            int ra = (wm + i * 16 + lrow) * QSTR + ks + lk8;
            int rb = (wn + i * 16 + lrow) * QSTR + ks + lk8;
            ah[i] = *(const bf16x8*)&qh[ra];
            al[i] = *(const bf16x8*)&ql[ra];
            bh[i] = *(const bf16x8*)&ch[rb];
            bl[i] = *(const bf16x8*)&cl[rb];
        }
        #pragma unroll
        for (int i = 0; i < 4; ++i)
            #pragma unroll
            for (int j = 0; j < 4; ++j) {
                acc[i][j] = __builtin_amdgcn_mfma_f32_16x16x32_bf16(ah[i], bh[j], acc[i][j], 0, 0, 0);
                acc[i][j] = __builtin_amdgcn_mfma_f32_16x16x32_bf16(ah[i], bl[j], acc[i][j], 0, 0, 0);
                acc[i][j] = __builtin_amdgcn_mfma_f32_16x16x32_bf16(al[i], bh[j], acc[i][j], 0, 0, 0);
            }
    }

    const int crow = (lane >> 4) << 2;
    const int ccol = lane & 15;
    for (int j = 0; j < 4; ++j) {
        int k = wn + j * 16 + ccol;
        float bwv = bw[k0 + k];
        float sc  = sqc[k];
        #pragma unroll
        for (int i = 0; i < 4; ++i) {
            #pragma unroll
            for (int r = 0; r < 4; ++r) {
                int b = wm + i * 16 + crow + r;
                float d2 = fmaxf(sqq[b] + sc - acc[i][j][r], 0.f);
                W[(size_t)(b0 + b) * Ksz + (k0 + k)] = __float2bfloat16(__expf(-bwv * d2));
            }
        }
    }
}

// ---------------------------------------------------------------------------
// Kernel 3: C[M][N] = A[M][K] * Bt[N][K]^T  (bf16 in, f32 out)
// EXACT r7 CHAMPION (83.6 us): 512 blocks, 256x256 tile, 16 K-tiles, 8-phase
// schedule, fragment register double-buffering, counted vmcnt/lgkm, plain
// stores. Restored verbatim after r8 (barrier surgery, neutral) and r9
// (32x32 shape, -9% from LDS bank conflicts) both failed to beat it.
// ---------------------------------------------------------------------------
#define TM2 256
#define TN2 256
#define BK2 64
#define NT2 16            // K-tiles

#define BAR()  __builtin_amdgcn_s_barrier()

#define MFMA_QUAD(Aa, Bb, MO, NO)                                              \
    _Pragma("unroll")                                                          \
    for (int ks = 0; ks < 2; ++ks)                                             \
        _Pragma("unroll")                                                      \
        for (int m = 0; m < 4; ++m)                                            \
            _Pragma("unroll")                                                  \
            for (int n = 0; n < 2; ++n)                                        \
                acc[MO + m][NO + n] = __builtin_amdgcn_mfma_f32_16x16x32_bf16( \
                    Aa[ks][m], Bb[ks][n], acc[MO + m][NO + n], 0, 0, 0);

__global__ __launch_bounds__(512, 2) void gemm_8ph(
    const __hip_bfloat16* __restrict__ A,   // W  [M][K]
    const __hip_bfloat16* __restrict__ Bt,  // Gt [N][K]
    float* __restrict__ C)                  // [M][N]
{
    __shared__ __attribute__((aligned(16))) __hip_bfloat16 As[2 * 2 * 128 * 64]; // 64 KB
    __shared__ __attribute__((aligned(16))) __hip_bfloat16 Bs[2 * 2 * 128 * 64]; // 64 KB

    const int t    = threadIdx.x;
    const int wave = t >> 6;
    const int lane = t & 63;

    // T1: bijective XCD swizzle (512 wgs, 8 XCDs, 64 per XCD; bx fastest for
    // A-panel reuse within the XCD chunk)
    const int wg  = blockIdx.x;
    const int swz = (wg & 7) * 64 + (wg >> 3);
    const int bx  = swz & 15;          // N: 4096/256 = 16
    const int by  = swz >> 4;          // M: 8192/256 = 32
    const int m0  = by * TM2;
    const int n0  = bx * TN2;

    const int wm   = (wave >> 2) * 128;  // 0 or 128
    const int wn   = (wave & 3) * 64;    // 0,64,128,192
    const int lrow = lane & 15;
    const int kg   = lane >> 4;          // 0..3

    f32x4 acc[8][4];
    #pragma unroll
    for (int i = 0; i < 8; ++i)
        #pragma unroll
        for (int j = 0; j < 4; ++j) acc[i][j] = (f32x4){0.f, 0.f, 0.f, 0.f};

    auto stageA = [&](int tt, int h) {
        __hip_bfloat16* lds = &As[(((tt & 1) << 1) + h) * 8192];
        const int row0 = m0 + (h << 6);
        const int kcol = (tt & 15) << 6;
        #pragma unroll
        for (int l = 0; l < 2; ++l) {
            int ch   = (l << 9) + t;
            int rl   = ch >> 3;
            int g8   = (ch & 7) ^ (rl & 7);
            int grow = row0 + ((rl >> 6) << 7) + (rl & 63);
            async_load16(A + (size_t)grow * Ksz + kcol + (g8 << 3), lds + (ch << 3));
        }
    };
    auto stageB = [&](int tt, int h) {
        __hip_bfloat16* lds = &Bs[(((tt & 1) << 1) + h) * 8192];
        const int row0 = n0 + (h << 5);
        const int kcol = (tt & 15) << 6;
        #pragma unroll
        for (int l = 0; l < 2; ++l) {
            int ch   = (l << 9) + t;
            int rl   = ch >> 3;
            int g8   = (ch & 7) ^ (rl & 7);
            int grow = row0 + ((rl >> 5) << 6) + (rl & 31);
            async_load16(Bt + (size_t)grow * Ksz + kcol + (g8 << 3), lds + (ch << 3));
        }
    };

    bf16x8 aC[2][4], aN[2][4], b0[2][2], b1[2][2];

    auto readA = [&](bf16x8 (&a)[2][4], int bb, int mh) {
        const __hip_bfloat16* base = &As[((bb << 1) + mh) * 8192];
        #pragma unroll
        for (int ks = 0; ks < 2; ++ks)
            #pragma unroll
            for (int m = 0; m < 4; ++m) {
                int rl = (wm >> 1) + m * 16 + lrow;
                int cc = ((((ks << 2) + kg) ^ (rl & 7)) << 3);
                a[ks][m] = *(const bf16x8*)&base[rl * 64 + cc];
            }
    };
    auto readB = [&](bf16x8 (&b)[2][2], int bb, int nh) {
        const __hip_bfloat16* base = &Bs[((bb << 1) + nh) * 8192];
        #pragma unroll
        for (int ks = 0; ks < 2; ++ks)
            #pragma unroll
            for (int n = 0; n < 2; ++n) {
                int rl = (wn >> 1) + n * 16 + lrow;
                int cc = ((((ks << 2) + kg) ^ (rl & 7)) << 3);
                b[ks][n] = *(const bf16x8*)&base[rl * 64 + cc];
            }
    };

    // --- prologue. Stage order defines the vmcnt queue:
    //     [A0(0), B0(0) | B1(0), A1(0), A0(1), B0(1), B1(1)]  (14 loads)
    //     vmcnt(10) forces A0(0),B0(0) -> pre-loop fragment reads are safe.
    stageA(0, 0); stageB(0, 0);
    stageB(0, 1); stageA(0, 1); stageA(1, 0); stageB(1, 0); stageB(1, 1);
    asm volatile("s_waitcnt vmcnt(10)" ::: "memory");
    BAR();
    readA(aC, 0, 0);
    readB(b0, 0, 0);          // 12 ds_reads in flight into regs

    #pragma unroll 2
    for (int tt = 0; tt < NT2; ++tt) {
        const int buf = tt & 1;

        // ---- phase 0: MFMA Q0(aC,b0) [read last ph3]; prefetch b1 <- B1(t)
        asm volatile("s_waitcnt vmcnt(8)" ::: "memory");   // B1(t) landed
        BAR();
        readB(b1, buf, 1);                                  // 4 ds
        stageA(tt + 1, 1);
        asm volatile("s_waitcnt lgkmcnt(4)" ::: "memory");  // aC/b0 done, b1 flies
        __builtin_amdgcn_s_setprio(1);
        MFMA_QUAD(aC, b0, 0, 0);
        __builtin_amdgcn_s_setprio(0);
        BAR();

        // ---- phase 1: MFMA Q1(aC,b1); prefetch aN <- A1(t)
        asm volatile("s_waitcnt vmcnt(8)" ::: "memory");   // A1(t) landed
        BAR();
        readA(aN, buf, 1);                                  // 8 ds
        stageA(tt + 2, 0);
        asm volatile("s_waitcnt lgkmcnt(8)" ::: "memory");  // b1 done, aN flies
        __builtin_amdgcn_s_setprio(1);
        MFMA_QUAD(aC, b1, 0, 2);
        __builtin_amdgcn_s_setprio(0);
        BAR();

        // ---- phase 2: MFMA Q2(aN,b1); no reads
        stageB(tt + 2, 0);
        BAR();
        asm volatile("s_waitcnt lgkmcnt(0)" ::: "memory");  // aN done (had ph1 to land)
        __builtin_amdgcn_s_setprio(1);
        MFMA_QUAD(aN, b1, 4, 2);
        __builtin_amdgcn_s_setprio(0);
        BAR();

        // ---- phase 3: MFMA Q3(aN,b0); cross-tile prefetch aC/b0 <- t+1
        stageB(tt + 2, 1);
        asm volatile("s_waitcnt vmcnt(10)" ::: "memory");  // A0(t+1),B0(t+1) landed
        BAR();
        __builtin_amdgcn_s_setprio(1);
        MFMA_QUAD(aN, b0, 4, 0);    // register-only; WAR keeps it before reads
        __builtin_amdgcn_s_setprio(0);
        readA(aC, buf ^ 1, 0);                              // 8 ds (next tile)
        readB(b0, buf ^ 1, 0);                              // 4 ds (next tile)
        BAR();
    }

    // --- epilogue: C/D layout col = lane&15, row = (lane>>4)*4 + reg
    //     PLAIN stores (champion behavior).
    const int crow = (lane >> 4) << 2;
    const int ccol = lane & 15;
    #pragma unroll
    for (int nj = 0; nj < 4; ++nj) {
        int gn = n0 + wn + ((nj >> 1) << 5) + ((nj & 1) << 4) + ccol;
        float diag = (gn % 65 == 0) ? 0.001f : 0.f;
        #pragma unroll
        for (int mi = 0; mi < 8; ++mi) {
            int gmb = m0 + wm + ((mi >> 2) << 6) + ((mi & 3) << 4) + crow;
            #pragma unroll
            for (int r = 0; r < 4; ++r) {
                C[(size_t)(gmb + r) * Nsz + gn] = acc[mi][nj][r] + diag;
            }
        }
    }
}

// ---------------------------------------------------------------------------
extern "C" void kernel_launch(void* const* d_in, const int* in_sizes, int n_in,
                              void* d_out, int out_size, void* d_ws, size_t ws_size,
                              hipStream_t stream) {
    const float* q  = (const float*)d_in[0];
    const float* c  = (const float*)d_in[1];
    const float* bw = (const float*)d_in[2];
    const float* G  = (const float*)d_in[3];
    float* out = (float*)d_out;

    __hip_bfloat16* W  = (__hip_bfloat16*)d_ws;                        // 16 MB
    __hip_bfloat16* Gt = (__hip_bfloat16*)((char*)d_ws + (size_t)16 * 1024 * 1024); // 8 MB

    prep_fused<<<dim3(512 + 1024), 256, 0, stream>>>(q, c, bw, G, W, Gt);
    gemm_8ph<<<dim3((Bsz / TM2) * (Nsz / TN2)), 512, 0, stream>>>(W, Gt, out);
}